// Round 11
// baseline (62.662 us; speedup 1.0000x reference)
//
#include <hip/hip_runtime.h>

// Shapes (fixed): T=8, S=512, B=8, D=512, H=8, hd=64, BH=64, NE=32, NI=64.
// out: (64, 512, 512) f32.
//
// Math reduction: sum_p telescopes to (sum_t Q_t)(sum_t K_t)^T * scale, so
//   p = (Xsum@Wq^T + 8 bq)(Xsum@Wk^T + 8 bk)^T / 64   (per bh batch, hd=64)
// The 1/64 is folded into Q at projection time.
//
// Q/K are stored in MFMA-FRAGMENT ORDER: [bh][blk16][half][lane][16B], so
// k_attn operand loads are fully-coalesced 1KB dwordx4 reads.
//
// exp-MLP epilogue: PAIRED value LUT float2[2048] = {f(t_i), f(t_{i+1})}
// over [-20,3]; one aligned 8B global load per element (L2-hot, indices
// cluster) + lerp = exact chord eval. NO LDS staging, NO publish barrier.
//
// R10 lesson: store-path traffic was NOT the limiter (76 vs 108 MB WRITE,
// same 43.5us) -> k_attn is now barrier-minimal (one __syncthreads) and
// LDS-free so residency is reg-limited only.
//
// REGISTER RULE (R4/R6/R8): VGPR+AGPR one budget; acc[8] structure fits
// launch_bounds(256,4); (256,5) spilled ~100MB. Keep (256,4).

#define T_  8
#define NE_ 32
#define NI_ 64

#define LUT_N   2048
#define LUT_LO  -20.0f
#define LUT_HI  3.0f
#define LUT_INVW (LUT_N / (LUT_HI - LUT_LO))     // 2048/23
#define LUT_W    ((LUT_HI - LUT_LO) / LUT_N)

typedef __attribute__((ext_vector_type(8))) short bf16x8;
typedef __attribute__((ext_vector_type(4))) float f32x4;
typedef __attribute__((ext_vector_type(4))) unsigned int u32x4;

// workspace layout, in ushort elements
#define XS_OFF 0u        // Xsum bf16 (4096 x 512)
#define WQ_OFF 2097152u  // Wq bf16 (512 x 512)
#define WK_OFF 2359296u  // Wk bf16
#define QB_OFF 2621440u  // Q bf16 frag-order (64*32*2*1024B), pre-scaled 1/64
#define KB_OFF 4718592u  // K bf16 frag-order
#define LUT_OFF 6815744u // float2 lut2[2048] = 16 KB (paired values)

__device__ inline unsigned short f2bf(float f) {
  union { float f; unsigned u; } v; v.f = f;
  unsigned r = v.u + 0x7FFFu + ((v.u >> 16) & 1u);
  return (unsigned short)(r >> 16);
}

__device__ inline void gload16(const void* g, void* l) {
  __builtin_amdgcn_global_load_lds(
      (const __attribute__((address_space(1))) void*)g,
      (__attribute__((address_space(3))) void*)l, 16, 0, 0);
}

// XOR-swizzled LDS read (k_proj GEMM tiles): 128B rows, slot ^ (row&7)
__device__ inline bf16x8 lds_read_swz(const unsigned short* base, int row, int byteoff) {
  int addr = row * 128 + (byteoff ^ ((row & 7) << 4));
  return *(const bf16x8*)((const char*)base + addr);
}

// inv-MLP with 4-way ILP accumulators (64-deep chain -> 16-deep)
__device__ inline float invmlp4(float x, const float* __restrict__ w1,
                                const float* __restrict__ b1,
                                const float* __restrict__ w2, float b2) {
  float a0 = b2, a1 = 0.f, a2 = 0.f, a3 = 0.f;
#pragma unroll
  for (int n = 0; n < NI_; n += 4) {
    a0 += w2[n + 0] * fmaxf(x * w1[n + 0] + b1[n + 0], 0.0f);
    a1 += w2[n + 1] * fmaxf(x * w1[n + 1] + b1[n + 1], 0.0f);
    a2 += w2[n + 2] * fmaxf(x * w1[n + 2] + b1[n + 2], 0.0f);
    a3 += w2[n + 3] * fmaxf(x * w1[n + 3] + b1[n + 3], 0.0f);
  }
  return (a0 + a1) + (a2 + a3);
}

__device__ inline float expmlp_exact(float t, const float* __restrict__ w1,
                                     const float* __restrict__ b1,
                                     const float* __restrict__ w2, float b2) {
  float a = b2;
#pragma unroll
  for (int n = 0; n < NE_; n++) a += w2[n] * fmaxf(t * w1[n] + b1[n], 0.0f);
  return a;
}

// ---------------------------------------------------------------------------
// Kernel 1: Xsum = sum_t sx[t] (f32->bf16, nt loads), Wq/Wk casts, LUT2.
__global__ __launch_bounds__(256) void k_pre(
    const float* __restrict__ sx, const float* __restrict__ wq,
    const float* __restrict__ wk, const float* __restrict__ ew1,
    const float* __restrict__ eb1, const float* __restrict__ ew2,
    const float* __restrict__ eb2p,
    unsigned short* __restrict__ xs, unsigned short* __restrict__ wqb,
    unsigned short* __restrict__ wkb, float2* __restrict__ lut2) {
  int bx = blockIdx.x, tid = threadIdx.x;
  if (bx < 2048) {
    size_t i = ((size_t)bx * 256 + tid) * 4;
    f32x4 a = __builtin_nontemporal_load((const f32x4*)(sx + i));
#pragma unroll
    for (int t = 1; t < T_; t++) {
      f32x4 v = __builtin_nontemporal_load((const f32x4*)(sx + (size_t)t * 2097152 + i));
      a += v;
    }
    ushort4 o; o.x = f2bf(a[0]); o.y = f2bf(a[1]); o.z = f2bf(a[2]); o.w = f2bf(a[3]);
    *(ushort4*)(xs + i) = o;
  } else if (bx < 2560) {
    const float* src = (bx < 2304) ? wq : wk;
    unsigned short* dst = (bx < 2304) ? wqb : wkb;
    int base = (bx < 2304) ? 2048 : 2304;
    size_t i = ((size_t)(bx - base) * 256 + tid) * 4;
    float4 a = *(const float4*)(src + i);
    ushort4 o; o.x = f2bf(a.x); o.y = f2bf(a.y); o.z = f2bf(a.z); o.w = f2bf(a.w);
    *(ushort4*)(dst + i) = o;
  } else {
    // paired value LUT: lut2[i] = {f(t_i), f(t_{i+1})}; shared edges exact.
    int i = (bx - 2560) * 256 + tid;
    if (i < LUT_N) {
      float b2 = eb2p[0];
      float tl = fmaf((float)i, LUT_W, LUT_LO);
      float th = fmaf((float)(i + 1), LUT_W, LUT_LO);
      lut2[i] = make_float2(expmlp_exact(tl, ew1, eb1, ew2, b2),
                            expmlp_exact(th, ew1, eb1, ew2, b2));
    }
  }
}

// ---------------------------------------------------------------------------
// Kernel 2: Y = Xsum(4096x512) @ W^T + 8*bias -> bf16 frag-order layout.
// z=0 (Q) additionally scaled by 1/64.  grid (32,4,2), 256 thr, 128x128 tile.
// Output goes through a 32KB LDS restage so global stores are 1KB-coalesced.
__global__ __launch_bounds__(256, 2) void k_proj(
    const unsigned short* __restrict__ xs, const unsigned short* __restrict__ wb,
    const float* __restrict__ bq, const float* __restrict__ bk,
    unsigned short* __restrict__ outb) {
  __shared__ unsigned short Sh[2][128 * 64];   // As = Sh[0], Bs = Sh[1]
  int tid = threadIdx.x;
  int lane = tid & 63, w = tid >> 6;
  int r0 = blockIdx.x * 128;
  int c0 = blockIdx.y * 128;
  int z = blockIdx.z;
  const unsigned short* W = wb + (size_t)z * 262144;
  const float* bias = z ? bk : bq;
  unsigned short* dst = outb + (size_t)z * 2097152;
  float sc = z ? 1.0f : (1.0f / 64.0f);

  int rgrp = lane >> 4, cl = lane & 15;
  int r0w = (w >> 1) * 64, c0w = (w & 1) * 64;

  f32x4 acc[4][4];
  f32x4 zero = {0.f, 0.f, 0.f, 0.f};
#pragma unroll
  for (int m = 0; m < 4; m++)
#pragma unroll
    for (int n = 0; n < 4; n++) acc[m][n] = zero;

  int rl = lane >> 3, slot = lane & 7;

  for (int kt = 0; kt < 8; kt++) {
    int k0 = kt * 64;
#pragma unroll
    for (int i = 0; i < 4; i++) {
      int chunk = w * 4 + i;
      int r = chunk * 8 + rl;
      int sw = (slot ^ (r & 7)) * 8;
      gload16(xs + (size_t)(r0 + r) * 512 + k0 + sw, (char*)Sh[0] + chunk * 1024);
      gload16(W + (size_t)(c0 + r) * 512 + k0 + sw, (char*)Sh[1] + chunk * 1024);
    }
    __syncthreads();
#pragma unroll
    for (int kb = 0; kb < 2; kb++) {
      bf16x8 af[4], bfr[4];
#pragma unroll
      for (int m = 0; m < 4; m++) af[m] = lds_read_swz(Sh[0], r0w + 16 * m + cl, kb * 64 + rgrp * 16);
#pragma unroll
      for (int n = 0; n < 4; n++) bfr[n] = lds_read_swz(Sh[1], c0w + 16 * n + cl, kb * 64 + rgrp * 16);
#pragma unroll
      for (int m = 0; m < 4; m++)
#pragma unroll
        for (int n = 0; n < 4; n++)
          acc[m][n] = __builtin_amdgcn_mfma_f32_16x16x32_bf16(af[m], bfr[n], acc[m][n], 0, 0, 0);
    }
    __syncthreads();
  }

  // stage: +8*bias, scale, cast -> LDS in frag-order [b][h][hh][512 ushort]
  unsigned short* Os = &Sh[0][0];   // 32 KB, GEMM tiles dead now
#pragma unroll
  for (int n = 0; n < 4; n++) {
    int cgl = c0w + 16 * n + cl;               // local col
    float bv = 8.0f * bias[c0 + cgl];
    int h = cgl >> 6, dh = cgl & 63;
    int hh = dh >> 5, rg2 = (dh >> 3) & 3, jj = dh & 7;
#pragma unroll
    for (int m = 0; m < 4; m++) {
#pragma unroll
      for (int j = 0; j < 4; j++) {
        int rgl = r0w + 16 * m + rgrp * 4 + j;  // local row
        int sl = rgl >> 3, b = rgl & 7;
        Os[(((b * 2 + h) * 2 + hh) * 512) + (rg2 * 16 + sl) * 8 + jj] =
            f2bf((acc[m][n][j] + bv) * sc);
      }
    }
  }
  __syncthreads();

  // coalesced store: 2048 x 16B units, 1KB per wave-instr
  int cb = r0 >> 7;
  int h0 = c0 >> 6;
#pragma unroll
  for (int i = 0; i < 8; i++) {
    int unit = i * 256 + tid;                  // [b:3][h:1][hh:1][inner:6]
    int b = unit >> 8, h = (unit >> 7) & 1, hh = (unit >> 6) & 1, inner = unit & 63;
    int bh = b * 8 + h0 + h;
    size_t du = ((size_t)((bh * 32 + cb) * 2 + hh)) * 512 + inner * 8;
    *(u32x4*)(dst + du) = *(const u32x4*)(Os + unit * 8);
  }
}

// ---------------------------------------------------------------------------
// Kernel 3: per (16-row block rb, bh): P = Q K^T (Q pre-scaled), LUT epilogue.
// grid 2048 x 256 thr (4 waves); wave w owns a 128-col strip, acc[8].
// BARRIER-MINIMAL: no LDS staging at all (LUT gathers hit L2 via paired
// float2 loads); single __syncthreads for the rowsum exchange. Scattered nt
// stores (duration-neutral vs restage, R9/R10 A/B). XCD-chunked blockIdx.
__global__ __launch_bounds__(256, 4) void k_attn(
    const unsigned short* __restrict__ qb, const unsigned short* __restrict__ kb,
    const float2* __restrict__ lut2,
    const float* __restrict__ iw1, const float* __restrict__ ib1,
    const float* __restrict__ iw2, const float* __restrict__ ib2p,
    float* __restrict__ out) {
  __shared__ float s_part[4][16];

  int tid = threadIdx.x;
  int lane = tid & 63, w = tid >> 6;   // w = 128-col strip
  int i = blockIdx.x;
  int xcd = i & 7, j2 = i >> 3;        // j2 in [0,256)
  int bh = xcd * 8 + (j2 >> 5);
  int rb = j2 & 31;                    // 16-row block
  int rgrp = lane >> 4, cl = lane & 15;

  // Q A-fragments for this block's 16 rows (1KB coalesced each)
  const char* Qb = (const char*)qb + (size_t)((bh * 32 + rb) * 2) * 1024;
  bf16x8 aF0 = *(const bf16x8*)(Qb + lane * 16);
  bf16x8 aF1 = *(const bf16x8*)(Qb + 1024 + lane * 16);

  const char* Kbase = (const char*)kb + (size_t)(bh * 32) * 2048;
  f32x4 zero = {0.f, 0.f, 0.f, 0.f};

  // col-block 0 (for tmax), every wave; p0 transient
  float tm1[4];
  {
    bf16x8 b0 = *(const bf16x8*)(Kbase + lane * 16);
    bf16x8 b1 = *(const bf16x8*)(Kbase + 1024 + lane * 16);
    f32x4 p0 = __builtin_amdgcn_mfma_f32_16x16x32_bf16(aF0, b0, zero, 0, 0, 0);
    p0 = __builtin_amdgcn_mfma_f32_16x16x32_bf16(aF1, b1, p0, 0, 0, 0);
    int src = lane & 48;  // cl==0 lane of this 16-group
#pragma unroll
    for (int j = 0; j < 4; j++) tm1[j] = __shfl(p0[j], src) - 1.0f;
  }

  f32x4 acc[8];
  __builtin_amdgcn_s_setprio(1);
#pragma unroll
  for (int f = 0; f < 8; f++) {
    const char* Kb = Kbase + (size_t)(w * 8 + f) * 2048;
    bf16x8 b0 = *(const bf16x8*)(Kb + lane * 16);
    bf16x8 b1 = *(const bf16x8*)(Kb + 1024 + lane * 16);
    acc[f] = __builtin_amdgcn_mfma_f32_16x16x32_bf16(aF0, b0, zero, 0, 0, 0);
    acc[f] = __builtin_amdgcn_mfma_f32_16x16x32_bf16(aF1, b1, acc[f], 0, 0, 0);
  }
  __builtin_amdgcn_s_setprio(0);

  // per-row index constants: u0 = p*INVW + cj; u0>0 <=> tp>-20
  const float C0 = -LUT_LO * LUT_INVW;
  float cj[4];
#pragma unroll
  for (int j = 0; j < 4; j++) cj[j] = fmaf(-tm1[j], LUT_INVW, C0);

  float rowsum[4] = {0.f, 0.f, 0.f, 0.f};
#pragma unroll
  for (int f = 0; f < 8; f++) {
#pragma unroll
    for (int j = 0; j < 4; j++) {
      float u0 = fmaf(acc[f][j], LUT_INVW, cj[j]);
      float u = fminf(fmaxf(u0, 0.0f), (float)LUT_N);    // [0, 2048]
      int bi = (int)fminf(u, (float)(LUT_N - 1));
      float frac = u - (float)bi;                        // [0, 1]
      float2 p2 = lut2[bi];                              // 8B L2-hot gather
      float xu = fmaf(frac, p2.y - p2.x, p2.x);
      xu = (u0 > 0.0f) ? xu : 0.0f;
      acc[f][j] = xu;
      rowsum[j] += xu;
    }
  }

  // row partial sums across the 16 cl lanes
#pragma unroll
  for (int j = 0; j < 4; j++) {
    float s = rowsum[j];
    s += __shfl_xor(s, 1);
    s += __shfl_xor(s, 2);
    s += __shfl_xor(s, 4);
    s += __shfl_xor(s, 8);
    if (cl == 0) s_part[w][rgrp * 4 + j] = s;
  }
  __syncthreads();   // the ONLY barrier

  // all-lane fac: lane computes fac for row = lane&15 (4x redundant per wave)
  float fac;
  {
    int myrow = lane & 15;
    float part = s_part[0][myrow] + s_part[1][myrow] +
                 s_part[2][myrow] + s_part[3][myrow];
    float b2 = ib2p[0];
    fac = invmlp4(part, iw1, ib1, iw2, b2);
    float pp2 = part * fac;
    if (pp2 > 1.5f) fac *= invmlp4(pp2, iw1, ib1, iw2, b2);
  }

  float* outb = out + ((size_t)bh * 512 + rb * 16) * 512;
#pragma unroll
  for (int j = 0; j < 4; j++) {
    int row = rgrp * 4 + j;
    float fj = __shfl(fac, (lane & 48) | row);
#pragma unroll
    for (int f = 0; f < 8; f++)
      __builtin_nontemporal_store(acc[f][j] * fj,
          &outb[(size_t)row * 512 + w * 128 + 16 * f + cl]);
  }
}

extern "C" void kernel_launch(void* const* d_in, const int* in_sizes, int n_in,
                              void* d_out, int out_size, void* d_ws, size_t ws_size,
                              hipStream_t stream) {
  (void)in_sizes; (void)n_in; (void)out_size; (void)ws_size;
  const float* sx  = (const float*)d_in[0];
  const float* wq  = (const float*)d_in[1];
  const float* wk  = (const float*)d_in[2];
  const float* bq  = (const float*)d_in[3];
  const float* bk  = (const float*)d_in[4];
  const float* ew1 = (const float*)d_in[5];
  const float* eb1 = (const float*)d_in[6];
  const float* ew2 = (const float*)d_in[7];
  const float* eb2 = (const float*)d_in[8];
  const float* iw1 = (const float*)d_in[9];
  const float* ib1 = (const float*)d_in[10];
  const float* iw2 = (const float*)d_in[11];
  const float* ib2 = (const float*)d_in[12];
  unsigned short* wsu = (unsigned short*)d_ws;
  float2* lut2 = (float2*)(wsu + LUT_OFF);
  float* out = (float*)d_out;

  k_pre<<<2568, 256, 0, stream>>>(sx, wq, wk, ew1, eb1, ew2, eb2,
                                  wsu + XS_OFF, wsu + WQ_OFF, wsu + WK_OFF, lut2);
  k_proj<<<dim3(32, 4, 2), 256, 0, stream>>>(wsu + XS_OFF, wsu + WQ_OFF, bq, bk, wsu + QB_OFF);
  k_attn<<<2048, 256, 0, stream>>>(wsu + QB_OFF, wsu + KB_OFF, lut2,
                                   iw1, ib1, iw2, ib2, out);
}

// Round 12
// 58.986 us; speedup vs baseline: 1.0623x; 1.0623x over previous
//
#include <hip/hip_runtime.h>

// Shapes (fixed): T=8, S=512, B=8, D=512, H=8, hd=64, BH=64, NE=32, NI=64.
// out: (64, 512, 512) f32.
//
// Math reduction: sum_p telescopes to (sum_t Q_t)(sum_t K_t)^T * scale, so
//   p = (Xsum@Wq^T + 8 bq)(Xsum@Wk^T + 8 bk)^T / 64   (per bh batch, hd=64)
// The 1/64 is folded into Q at projection time.
//
// Q/K are stored in MFMA-FRAGMENT ORDER: [bh][blk16][half][lane][16B], so
// k_attn operand loads are fully-coalesced 1KB dwordx4 reads.
//
// exp-MLP epilogue: 2048-bucket CHORD LUT (alpha,beta float2, 16KB LDS) over
// [-20,3]: xu = alpha*tp + beta = exact PWL eval off knot buckets. One
// ds_read_b64 + one fmaf per element (this beat value-LUT interp by ~3 VALU
// and a dependent op chain - R9/R11 regression).
//
// LADDER ANCHOR (Round-7 bench, 55.5us total): this k_attn structure -
// (256,4), acc[8], LDS chord LUT, tid<16 fac, scattered nt stores. R8-R11
// bundled value-interp + ALL-LANE redundant inv-MLP (+32K busy cyc/CU) and
// regressed 5-7us. This file reverts to the anchor; only deltas: 16KB LUT
// (was 32KB) and ILP-4 fac.
//
// REGISTER RULE (R4/R6/R8): VGPR+AGPR one budget; acc[8] fits (256,4)
// (VGPR 64, zero scratch); (256,5) spilled ~100MB. Never tighten past 4.

#define T_  8
#define NE_ 32
#define NI_ 64

#define LUT_N   2048
#define LUT_LO  -20.0f
#define LUT_HI  3.0f
#define LUT_INVW (LUT_N / (LUT_HI - LUT_LO))     // 2048/23
#define LUT_W    ((LUT_HI - LUT_LO) / LUT_N)

typedef __attribute__((ext_vector_type(8))) short bf16x8;
typedef __attribute__((ext_vector_type(4))) float f32x4;
typedef __attribute__((ext_vector_type(4))) unsigned int u32x4;

// workspace layout, in ushort elements
#define XS_OFF 0u        // Xsum bf16 (4096 x 512)
#define WQ_OFF 2097152u  // Wq bf16 (512 x 512)
#define WK_OFF 2359296u  // Wk bf16
#define QB_OFF 2621440u  // Q bf16 frag-order (64*32*2*1024B), pre-scaled 1/64
#define KB_OFF 4718592u  // K bf16 frag-order
#define LUT_OFF 6815744u // float2 lut[2048] = 16 KB (chord alpha,beta)

__device__ inline unsigned short f2bf(float f) {
  union { float f; unsigned u; } v; v.f = f;
  unsigned r = v.u + 0x7FFFu + ((v.u >> 16) & 1u);
  return (unsigned short)(r >> 16);
}

__device__ inline void gload16(const void* g, void* l) {
  __builtin_amdgcn_global_load_lds(
      (const __attribute__((address_space(1))) void*)g,
      (__attribute__((address_space(3))) void*)l, 16, 0, 0);
}

// XOR-swizzled LDS read (k_proj GEMM tiles): 128B rows, slot ^ (row&7)
__device__ inline bf16x8 lds_read_swz(const unsigned short* base, int row, int byteoff) {
  int addr = row * 128 + (byteoff ^ ((row & 7) << 4));
  return *(const bf16x8*)((const char*)base + addr);
}

// inv-MLP with 4-way ILP accumulators (64-deep chain -> 16-deep)
__device__ inline float invmlp4(float x, const float* __restrict__ w1,
                                const float* __restrict__ b1,
                                const float* __restrict__ w2, float b2) {
  float a0 = b2, a1 = 0.f, a2 = 0.f, a3 = 0.f;
#pragma unroll
  for (int n = 0; n < NI_; n += 4) {
    a0 += w2[n + 0] * fmaxf(x * w1[n + 0] + b1[n + 0], 0.0f);
    a1 += w2[n + 1] * fmaxf(x * w1[n + 1] + b1[n + 1], 0.0f);
    a2 += w2[n + 2] * fmaxf(x * w1[n + 2] + b1[n + 2], 0.0f);
    a3 += w2[n + 3] * fmaxf(x * w1[n + 3] + b1[n + 3], 0.0f);
  }
  return (a0 + a1) + (a2 + a3);
}

__device__ inline float expmlp_exact(float t, const float* __restrict__ w1,
                                     const float* __restrict__ b1,
                                     const float* __restrict__ w2, float b2) {
  float a = b2;
#pragma unroll
  for (int n = 0; n < NE_; n++) a += w2[n] * fmaxf(t * w1[n] + b1[n], 0.0f);
  return a;
}

// ---------------------------------------------------------------------------
// Kernel 1: Xsum = sum_t sx[t] (f32->bf16, nt loads), Wq/Wk casts, chord LUT.
__global__ __launch_bounds__(256) void k_pre(
    const float* __restrict__ sx, const float* __restrict__ wq,
    const float* __restrict__ wk, const float* __restrict__ ew1,
    const float* __restrict__ eb1, const float* __restrict__ ew2,
    const float* __restrict__ eb2p,
    unsigned short* __restrict__ xs, unsigned short* __restrict__ wqb,
    unsigned short* __restrict__ wkb, float2* __restrict__ lut) {
  int bx = blockIdx.x, tid = threadIdx.x;
  if (bx < 2048) {
    size_t i = ((size_t)bx * 256 + tid) * 4;
    f32x4 a = __builtin_nontemporal_load((const f32x4*)(sx + i));
#pragma unroll
    for (int t = 1; t < T_; t++) {
      f32x4 v = __builtin_nontemporal_load((const f32x4*)(sx + (size_t)t * 2097152 + i));
      a += v;
    }
    ushort4 o; o.x = f2bf(a[0]); o.y = f2bf(a[1]); o.z = f2bf(a[2]); o.w = f2bf(a[3]);
    *(ushort4*)(xs + i) = o;
  } else if (bx < 2560) {
    const float* src = (bx < 2304) ? wq : wk;
    unsigned short* dst = (bx < 2304) ? wqb : wkb;
    int base = (bx < 2304) ? 2048 : 2304;
    size_t i = ((size_t)(bx - base) * 256 + tid) * 4;
    float4 a = *(const float4*)(src + i);
    ushort4 o; o.x = f2bf(a.x); o.y = f2bf(a.y); o.z = f2bf(a.z); o.w = f2bf(a.w);
    *(ushort4*)(dst + i) = o;
  } else {
    // chord LUT: bucket i over [t_i, t_{i+1}]; edges evaluated identically by
    // neighbors -> exact continuity.
    int i = (bx - 2560) * 256 + tid;
    if (i < LUT_N) {
      float b2 = eb2p[0];
      float tl = fmaf((float)i, LUT_W, LUT_LO);
      float th = fmaf((float)(i + 1), LUT_W, LUT_LO);
      float el = expmlp_exact(tl, ew1, eb1, ew2, b2);
      float eh = expmlp_exact(th, ew1, eb1, ew2, b2);
      float alpha = (eh - el) * LUT_INVW;
      float beta = fmaf(-alpha, tl, el);
      lut[i] = make_float2(alpha, beta);
    }
  }
}

// ---------------------------------------------------------------------------
// Kernel 2: Y = Xsum(4096x512) @ W^T + 8*bias -> bf16 frag-order layout.
// z=0 (Q) additionally scaled by 1/64.  grid (32,4,2), 256 thr, 128x128 tile.
// Output goes through a 32KB LDS restage so global stores are 1KB-coalesced.
__global__ __launch_bounds__(256, 2) void k_proj(
    const unsigned short* __restrict__ xs, const unsigned short* __restrict__ wb,
    const float* __restrict__ bq, const float* __restrict__ bk,
    unsigned short* __restrict__ outb) {
  __shared__ unsigned short Sh[2][128 * 64];   // As = Sh[0], Bs = Sh[1]
  int tid = threadIdx.x;
  int lane = tid & 63, w = tid >> 6;
  int r0 = blockIdx.x * 128;
  int c0 = blockIdx.y * 128;
  int z = blockIdx.z;
  const unsigned short* W = wb + (size_t)z * 262144;
  const float* bias = z ? bk : bq;
  unsigned short* dst = outb + (size_t)z * 2097152;
  float sc = z ? 1.0f : (1.0f / 64.0f);

  int rgrp = lane >> 4, cl = lane & 15;
  int r0w = (w >> 1) * 64, c0w = (w & 1) * 64;

  f32x4 acc[4][4];
  f32x4 zero = {0.f, 0.f, 0.f, 0.f};
#pragma unroll
  for (int m = 0; m < 4; m++)
#pragma unroll
    for (int n = 0; n < 4; n++) acc[m][n] = zero;

  int rl = lane >> 3, slot = lane & 7;

  for (int kt = 0; kt < 8; kt++) {
    int k0 = kt * 64;
#pragma unroll
    for (int i = 0; i < 4; i++) {
      int chunk = w * 4 + i;
      int r = chunk * 8 + rl;
      int sw = (slot ^ (r & 7)) * 8;
      gload16(xs + (size_t)(r0 + r) * 512 + k0 + sw, (char*)Sh[0] + chunk * 1024);
      gload16(W + (size_t)(c0 + r) * 512 + k0 + sw, (char*)Sh[1] + chunk * 1024);
    }
    __syncthreads();
#pragma unroll
    for (int kb = 0; kb < 2; kb++) {
      bf16x8 af[4], bfr[4];
#pragma unroll
      for (int m = 0; m < 4; m++) af[m] = lds_read_swz(Sh[0], r0w + 16 * m + cl, kb * 64 + rgrp * 16);
#pragma unroll
      for (int n = 0; n < 4; n++) bfr[n] = lds_read_swz(Sh[1], c0w + 16 * n + cl, kb * 64 + rgrp * 16);
#pragma unroll
      for (int m = 0; m < 4; m++)
#pragma unroll
        for (int n = 0; n < 4; n++)
          acc[m][n] = __builtin_amdgcn_mfma_f32_16x16x32_bf16(af[m], bfr[n], acc[m][n], 0, 0, 0);
    }
    __syncthreads();
  }

  // stage: +8*bias, scale, cast -> LDS in frag-order [b][h][hh][512 ushort]
  unsigned short* Os = &Sh[0][0];   // 32 KB, GEMM tiles dead now
#pragma unroll
  for (int n = 0; n < 4; n++) {
    int cgl = c0w + 16 * n + cl;               // local col
    float bv = 8.0f * bias[c0 + cgl];
    int h = cgl >> 6, dh = cgl & 63;
    int hh = dh >> 5, rg2 = (dh >> 3) & 3, jj = dh & 7;
#pragma unroll
    for (int m = 0; m < 4; m++) {
#pragma unroll
      for (int j = 0; j < 4; j++) {
        int rgl = r0w + 16 * m + rgrp * 4 + j;  // local row
        int sl = rgl >> 3, b = rgl & 7;
        Os[(((b * 2 + h) * 2 + hh) * 512) + (rg2 * 16 + sl) * 8 + jj] =
            f2bf((acc[m][n][j] + bv) * sc);
      }
    }
  }
  __syncthreads();

  // coalesced store: 2048 x 16B units, 1KB per wave-instr
  int cb = r0 >> 7;
  int h0 = c0 >> 6;
#pragma unroll
  for (int i = 0; i < 8; i++) {
    int unit = i * 256 + tid;                  // [b:3][h:1][hh:1][inner:6]
    int b = unit >> 8, h = (unit >> 7) & 1, hh = (unit >> 6) & 1, inner = unit & 63;
    int bh = b * 8 + h0 + h;
    size_t du = ((size_t)((bh * 32 + cb) * 2 + hh)) * 512 + inner * 8;
    *(u32x4*)(dst + du) = *(const u32x4*)(Os + unit * 8);
  }
}

// ---------------------------------------------------------------------------
// Kernel 3 (= Round-7 anchor): per (16-row block rb, bh): P = Q K^T, chord
// LUT epilogue. grid 2048 x 256 thr (4 waves); wave w = 128-col strip, acc[8].
// launch_bounds(256,4): proven no-spill. XCD-chunked blockIdx.
// tmax per-wave (extra col-block-0 MFMA) + shfl; tid<16 fac (ILP-4).
__global__ __launch_bounds__(256, 4) void k_attn(
    const unsigned short* __restrict__ qb, const unsigned short* __restrict__ kb,
    const float2* __restrict__ lutg,
    const float* __restrict__ iw1, const float* __restrict__ ib1,
    const float* __restrict__ iw2, const float* __restrict__ ib2p,
    float* __restrict__ out) {
  __shared__ float2 Lut[LUT_N];   // 16 KB
  __shared__ float s_part[4][16];
  __shared__ float s_fac[16];

  int tid = threadIdx.x;
  int lane = tid & 63, w = tid >> 6;   // w = 128-col strip
  int i = blockIdx.x;
  int xcd = i & 7, j2 = i >> 3;        // j2 in [0,256)
  int bh = xcd * 8 + (j2 >> 5);
  int rb = j2 & 31;                    // 16-row block
  int rgrp = lane >> 4, cl = lane & 15;

  // stage LUT: 16 KB via gload16 (4 waves x 4 chunks of 1KB); published by
  // the barrier AFTER the MFMA phase (loads land under compute).
#pragma unroll
  for (int c = 0; c < 4; c++) {
    int chunk = w * 4 + c;
    gload16((const char*)lutg + chunk * 1024 + lane * 16, (char*)Lut + chunk * 1024);
  }

  // Q A-fragments for this block's 16 rows (1KB coalesced each)
  const char* Qb = (const char*)qb + (size_t)((bh * 32 + rb) * 2) * 1024;
  bf16x8 aF0 = *(const bf16x8*)(Qb + lane * 16);
  bf16x8 aF1 = *(const bf16x8*)(Qb + 1024 + lane * 16);

  const char* Kbase = (const char*)kb + (size_t)(bh * 32) * 2048;
  f32x4 zero = {0.f, 0.f, 0.f, 0.f};

  // col-block 0 (for tmax), every wave; p0 transient
  float tm1[4];
  {
    bf16x8 b0 = *(const bf16x8*)(Kbase + lane * 16);
    bf16x8 b1 = *(const bf16x8*)(Kbase + 1024 + lane * 16);
    f32x4 p0 = __builtin_amdgcn_mfma_f32_16x16x32_bf16(aF0, b0, zero, 0, 0, 0);
    p0 = __builtin_amdgcn_mfma_f32_16x16x32_bf16(aF1, b1, p0, 0, 0, 0);
    int src = lane & 48;  // cl==0 lane of this 16-group
#pragma unroll
    for (int j = 0; j < 4; j++) tm1[j] = __shfl(p0[j], src) - 1.0f;
  }

  f32x4 acc[8];
#pragma unroll
  for (int f = 0; f < 8; f++) {
    const char* Kb = Kbase + (size_t)(w * 8 + f) * 2048;
    bf16x8 b0 = *(const bf16x8*)(Kb + lane * 16);
    bf16x8 b1 = *(const bf16x8*)(Kb + 1024 + lane * 16);
    acc[f] = __builtin_amdgcn_mfma_f32_16x16x32_bf16(aF0, b0, zero, 0, 0, 0);
    acc[f] = __builtin_amdgcn_mfma_f32_16x16x32_bf16(aF1, b1, acc[f], 0, 0, 0);
  }

  __syncthreads();  // LUT visible (gloads landed during MFMA phase)

  const float C0 = -LUT_LO * LUT_INVW;
  float rowsum[4] = {0.f, 0.f, 0.f, 0.f};
#pragma unroll
  for (int f = 0; f < 8; f++) {
#pragma unroll
    for (int j = 0; j < 4; j++) {
      float tp = fminf(acc[f][j] - tm1[j], 3.0f);
      float u = fmaf(tp, LUT_INVW, C0);
      u = fminf(fmaxf(u, 0.0f), (float)(LUT_N - 1));  // v_med3
      float2 ab = Lut[(int)u];
      float xu = fmaf(ab.x, tp, ab.y);
      xu = (tp > -20.0f) ? xu : 0.0f;
      acc[f][j] = xu;
      rowsum[j] += xu;
    }
  }

  // row partial sums across the 16 cl lanes
#pragma unroll
  for (int j = 0; j < 4; j++) {
    float s = rowsum[j];
    s += __shfl_xor(s, 1);
    s += __shfl_xor(s, 2);
    s += __shfl_xor(s, 4);
    s += __shfl_xor(s, 8);
    if (cl == 0) s_part[w][rgrp * 4 + j] = s;
  }
  __syncthreads();

  if (tid < 16) {
    float part = s_part[0][tid] + s_part[1][tid] + s_part[2][tid] + s_part[3][tid];
    float b2 = ib2p[0];
    float fac = invmlp4(part, iw1, ib1, iw2, b2);
    float pp2 = part * fac;
    if (pp2 > 1.5f) fac *= invmlp4(pp2, iw1, ib1, iw2, b2);
    s_fac[tid] = fac;
  }
  __syncthreads();

  float* outb = out + ((size_t)bh * 512 + rb * 16) * 512;
#pragma unroll
  for (int j = 0; j < 4; j++) {
    int row = rgrp * 4 + j;
    float fac = s_fac[row];
#pragma unroll
    for (int f = 0; f < 8; f++)
      __builtin_nontemporal_store(acc[f][j] * fac,
          &outb[(size_t)row * 512 + w * 128 + 16 * f + cl]);
  }
}

extern "C" void kernel_launch(void* const* d_in, const int* in_sizes, int n_in,
                              void* d_out, int out_size, void* d_ws, size_t ws_size,
                              hipStream_t stream) {
  (void)in_sizes; (void)n_in; (void)out_size; (void)ws_size;
  const float* sx  = (const float*)d_in[0];
  const float* wq  = (const float*)d_in[1];
  const float* wk  = (const float*)d_in[2];
  const float* bq  = (const float*)d_in[3];
  const float* bk  = (const float*)d_in[4];
  const float* ew1 = (const float*)d_in[5];
  const float* eb1 = (const float*)d_in[6];
  const float* ew2 = (const float*)d_in[7];
  const float* eb2 = (const float*)d_in[8];
  const float* iw1 = (const float*)d_in[9];
  const float* ib1 = (const float*)d_in[10];
  const float* iw2 = (const float*)d_in[11];
  const float* ib2 = (const float*)d_in[12];
  unsigned short* wsu = (unsigned short*)d_ws;
  float2* lut = (float2*)(wsu + LUT_OFF);
  float* out = (float*)d_out;

  k_pre<<<2568, 256, 0, stream>>>(sx, wq, wk, ew1, eb1, ew2, eb2,
                                  wsu + XS_OFF, wsu + WQ_OFF, wsu + WK_OFF, lut);
  k_proj<<<dim3(32, 4, 2), 256, 0, stream>>>(wsu + XS_OFF, wsu + WQ_OFF, bq, bk, wsu + QB_OFF);
  k_attn<<<2048, 256, 0, stream>>>(wsu + QB_OFF, wsu + KB_OFF, lut,
                                   iw1, ib1, iw2, ib2, out);
}

// Round 13
// 56.624 us; speedup vs baseline: 1.1066x; 1.0417x over previous
//
#include <hip/hip_runtime.h>

// Shapes (fixed): T=8, S=512, B=8, D=512, H=8, hd=64, BH=64, NE=32, NI=64.
// out: (64, 512, 512) f32.
//
// Math reduction: sum_p telescopes to (sum_t Q_t)(sum_t K_t)^T * scale, so
//   p = (Xsum@Wq^T + 8 bq)(Xsum@Wk^T + 8 bk)^T / 64   (per bh batch, hd=64)
// The 1/64 is folded into Q at projection time.
//
// Q/K are stored in MFMA-FRAGMENT ORDER: [bh][blk16][half][lane][16B], so
// k_attn operand loads are fully-coalesced 1KB dwordx4 reads.
//
// exp-MLP epilogue: 2048-bucket chord LUT in INDEX SPACE (a',b' float2,
// 16KB LDS): xu = a'*u + b' where u = (tp-LO)*INVW; exact PWL eval off knot
// buckets, exact at clamp ends (u=N -> f(3.0); u0<=0 masked = tp<=-20).
//
// LADDER ANCHOR (R7 bench, 55.5us): k_attn = (256,4), acc[8], LDS chord LUT,
// tid<16 fac, scattered nt stores. R8-R11 regressions were bundled epilogue
// changes. This round: only deltas = u-domain LUT (1-2 fewer VALU/elem) and
// k_proj 64x128 tiles (512 blocks = 2 blocks/CU, was 1 -> occupancy fix).
//
// REGISTER RULE (R4/R6/R8): VGPR+AGPR one budget; acc[8] fits (256,4)
// (VGPR 64, zero scratch); (256,5) spilled ~100MB. Never tighten past 4.

#define T_  8
#define NE_ 32
#define NI_ 64

#define LUT_N   2048
#define LUT_LO  -20.0f
#define LUT_HI  3.0f
#define LUT_INVW (LUT_N / (LUT_HI - LUT_LO))     // 2048/23
#define LUT_W    ((LUT_HI - LUT_LO) / LUT_N)

typedef __attribute__((ext_vector_type(8))) short bf16x8;
typedef __attribute__((ext_vector_type(4))) float f32x4;
typedef __attribute__((ext_vector_type(4))) unsigned int u32x4;

// workspace layout, in ushort elements
#define XS_OFF 0u        // Xsum bf16 (4096 x 512)
#define WQ_OFF 2097152u  // Wq bf16 (512 x 512)
#define WK_OFF 2359296u  // Wk bf16
#define QB_OFF 2621440u  // Q bf16 frag-order (64*32*2*1024B), pre-scaled 1/64
#define KB_OFF 4718592u  // K bf16 frag-order
#define LUT_OFF 6815744u // float2 lut[2048] = 16 KB (index-space chord a',b')

__device__ inline unsigned short f2bf(float f) {
  union { float f; unsigned u; } v; v.f = f;
  unsigned r = v.u + 0x7FFFu + ((v.u >> 16) & 1u);
  return (unsigned short)(r >> 16);
}

__device__ inline void gload16(const void* g, void* l) {
  __builtin_amdgcn_global_load_lds(
      (const __attribute__((address_space(1))) void*)g,
      (__attribute__((address_space(3))) void*)l, 16, 0, 0);
}

// XOR-swizzled LDS read (k_proj GEMM tiles): 128B rows, slot ^ (row&7)
__device__ inline bf16x8 lds_read_swz(const unsigned short* base, int row, int byteoff) {
  int addr = row * 128 + (byteoff ^ ((row & 7) << 4));
  return *(const bf16x8*)((const char*)base + addr);
}

// inv-MLP with 4-way ILP accumulators (64-deep chain -> 16-deep)
__device__ inline float invmlp4(float x, const float* __restrict__ w1,
                                const float* __restrict__ b1,
                                const float* __restrict__ w2, float b2) {
  float a0 = b2, a1 = 0.f, a2 = 0.f, a3 = 0.f;
#pragma unroll
  for (int n = 0; n < NI_; n += 4) {
    a0 += w2[n + 0] * fmaxf(x * w1[n + 0] + b1[n + 0], 0.0f);
    a1 += w2[n + 1] * fmaxf(x * w1[n + 1] + b1[n + 1], 0.0f);
    a2 += w2[n + 2] * fmaxf(x * w1[n + 2] + b1[n + 2], 0.0f);
    a3 += w2[n + 3] * fmaxf(x * w1[n + 3] + b1[n + 3], 0.0f);
  }
  return (a0 + a1) + (a2 + a3);
}

__device__ inline float expmlp_exact(float t, const float* __restrict__ w1,
                                     const float* __restrict__ b1,
                                     const float* __restrict__ w2, float b2) {
  float a = b2;
#pragma unroll
  for (int n = 0; n < NE_; n++) a += w2[n] * fmaxf(t * w1[n] + b1[n], 0.0f);
  return a;
}

// ---------------------------------------------------------------------------
// Kernel 1: Xsum = sum_t sx[t] (f32->bf16, nt loads), Wq/Wk casts, chord LUT.
__global__ __launch_bounds__(256) void k_pre(
    const float* __restrict__ sx, const float* __restrict__ wq,
    const float* __restrict__ wk, const float* __restrict__ ew1,
    const float* __restrict__ eb1, const float* __restrict__ ew2,
    const float* __restrict__ eb2p,
    unsigned short* __restrict__ xs, unsigned short* __restrict__ wqb,
    unsigned short* __restrict__ wkb, float2* __restrict__ lut) {
  int bx = blockIdx.x, tid = threadIdx.x;
  if (bx < 2048) {
    size_t i = ((size_t)bx * 256 + tid) * 4;
    f32x4 a = __builtin_nontemporal_load((const f32x4*)(sx + i));
#pragma unroll
    for (int t = 1; t < T_; t++) {
      f32x4 v = __builtin_nontemporal_load((const f32x4*)(sx + (size_t)t * 2097152 + i));
      a += v;
    }
    ushort4 o; o.x = f2bf(a[0]); o.y = f2bf(a[1]); o.z = f2bf(a[2]); o.w = f2bf(a[3]);
    *(ushort4*)(xs + i) = o;
  } else if (bx < 2560) {
    const float* src = (bx < 2304) ? wq : wk;
    unsigned short* dst = (bx < 2304) ? wqb : wkb;
    int base = (bx < 2304) ? 2048 : 2304;
    size_t i = ((size_t)(bx - base) * 256 + tid) * 4;
    float4 a = *(const float4*)(src + i);
    ushort4 o; o.x = f2bf(a.x); o.y = f2bf(a.y); o.z = f2bf(a.z); o.w = f2bf(a.w);
    *(ushort4*)(dst + i) = o;
  } else {
    // index-space chord LUT: xu(u) = a'*u + b' on bucket i (u in [i, i+1]);
    // a' = f(t_{i+1})-f(t_i), b' = f(t_i) - a'*i. Edges shared -> continuity.
    int i = (bx - 2560) * 256 + tid;
    if (i < LUT_N) {
      float b2 = eb2p[0];
      float tl = fmaf((float)i, LUT_W, LUT_LO);
      float th = fmaf((float)(i + 1), LUT_W, LUT_LO);
      float el = expmlp_exact(tl, ew1, eb1, ew2, b2);
      float eh = expmlp_exact(th, ew1, eb1, ew2, b2);
      float ap = eh - el;
      float bp = fmaf(-ap, (float)i, el);
      lut[i] = make_float2(ap, bp);
    }
  }
}

// ---------------------------------------------------------------------------
// Kernel 2: Y = Xsum(4096x512) @ W^T + 8*bias -> bf16 frag-order layout.
// z=0 (Q) additionally scaled by 1/64.  grid (64,4,2) = 512 blocks
// (2 blocks/CU, occupancy fix vs 256-block 128x128 version), 256 thr,
// 64x128 tile: 4 waves of 32x64 (acc[2][4] = 32 AGPR). LDS 24KB.
// Output restaged via LDS (reuses Bs) -> coalesced 16B stores.
__global__ __launch_bounds__(256, 2) void k_proj(
    const unsigned short* __restrict__ xs, const unsigned short* __restrict__ wb,
    const float* __restrict__ bq, const float* __restrict__ bk,
    unsigned short* __restrict__ outb) {
  __shared__ unsigned short As[64 * 64];    // 8 KB
  __shared__ unsigned short Bs[128 * 64];   // 16 KB (reused as Os)
  int tid = threadIdx.x;
  int lane = tid & 63, w = tid >> 6;
  int r0 = blockIdx.x * 64;                 // bx in [0,64)
  int c0 = blockIdx.y * 128;                // by in [0,4)
  int z = blockIdx.z;
  const unsigned short* W = wb + (size_t)z * 262144;
  const float* bias = z ? bk : bq;
  unsigned short* dst = outb + (size_t)z * 2097152;
  float sc = z ? 1.0f : (1.0f / 64.0f);

  int rgrp = lane >> 4, cl = lane & 15;
  int r0w = (w >> 1) * 32, c0w = (w & 1) * 64;

  f32x4 acc[2][4];
  f32x4 zero = {0.f, 0.f, 0.f, 0.f};
#pragma unroll
  for (int m = 0; m < 2; m++)
#pragma unroll
    for (int n = 0; n < 4; n++) acc[m][n] = zero;

  int rl = lane >> 3, slot = lane & 7;

  for (int kt = 0; kt < 8; kt++) {
    int k0 = kt * 64;
    // A: 8 chunks (64 rows), 2 per wave
#pragma unroll
    for (int i = 0; i < 2; i++) {
      int chunk = w * 2 + i;
      int r = chunk * 8 + rl;
      int sw = (slot ^ (r & 7)) * 8;
      gload16(xs + (size_t)(r0 + r) * 512 + k0 + sw, (char*)As + chunk * 1024);
    }
    // B: 16 chunks (128 rows), 4 per wave
#pragma unroll
    for (int i = 0; i < 4; i++) {
      int chunk = w * 4 + i;
      int r = chunk * 8 + rl;
      int sw = (slot ^ (r & 7)) * 8;
      gload16(W + (size_t)(c0 + r) * 512 + k0 + sw, (char*)Bs + chunk * 1024);
    }
    __syncthreads();
#pragma unroll
    for (int kb = 0; kb < 2; kb++) {
      bf16x8 af[2], bfr[4];
#pragma unroll
      for (int m = 0; m < 2; m++) af[m] = lds_read_swz(As, r0w + 16 * m + cl, kb * 64 + rgrp * 16);
#pragma unroll
      for (int n = 0; n < 4; n++) bfr[n] = lds_read_swz(Bs, c0w + 16 * n + cl, kb * 64 + rgrp * 16);
#pragma unroll
      for (int m = 0; m < 2; m++)
#pragma unroll
        for (int n = 0; n < 4; n++)
          acc[m][n] = __builtin_amdgcn_mfma_f32_16x16x32_bf16(af[m], bfr[n], acc[m][n], 0, 0, 0);
    }
    __syncthreads();
  }

  // stage: +8*bias, scale, cast -> Os (=Bs) in frag-order
  // local layout: [b:8][hl:2][hh:2][rg2:4][clsl:8][jj:8] ushort = 16 KB
  unsigned short* Os = Bs;
#pragma unroll
  for (int n = 0; n < 4; n++) {
    int cgl = c0w + 16 * n + cl;               // [0,128)
    float bv = 8.0f * bias[c0 + cgl];
    int hl = cgl >> 6, dh = cgl & 63;
    int hh = dh >> 5, rg2 = (dh >> 3) & 3, jj = dh & 7;
#pragma unroll
    for (int m = 0; m < 2; m++) {
#pragma unroll
      for (int j = 0; j < 4; j++) {
        int rgl = r0w + 16 * m + rgrp * 4 + j;  // [0,64)
        int b = rgl & 7, clsl = rgl >> 3;       // [0,8)
        Os[((((b * 2 + hl) * 2 + hh) * 4 + rg2) * 8 + clsl) * 8 + jj] =
            f2bf((acc[m][n][j] + bv) * sc);
      }
    }
  }
  __syncthreads();

  // coalesced store: 1024 x 16B units
  int cb = blockIdx.x >> 1;
  int clsbase = (blockIdx.x & 1) * 8;
  int h0 = c0 >> 6;                             // by*2
#pragma unroll
  for (int i2 = 0; i2 < 4; i2++) {
    int unit = i2 * 256 + tid;                  // [b:3][hl:1][hh:1][rg2:2][clsl:3]
    int clsl = unit & 7, rg2 = (unit >> 3) & 3, hh = (unit >> 5) & 1;
    int hl = (unit >> 6) & 1, b = unit >> 7;
    int bh = b * 8 + h0 + hl;
    size_t du = ((size_t)((bh * 32 + cb) * 2 + hh)) * 512 + (rg2 * 16 + clsbase + clsl) * 8;
    *(u32x4*)(dst + du) = *(const u32x4*)(Os + unit * 8);
  }
}

// ---------------------------------------------------------------------------
// Kernel 3 (R7 anchor + u-domain LUT): per (16-row block rb, bh): P = Q K^T,
// chord LUT epilogue. grid 2048 x 256 thr (4 waves); wave w = 128-col strip,
// acc[8]. launch_bounds(256,4): proven no-spill. XCD-chunked blockIdx.
// tmax per-wave (extra col-block-0 MFMA) + shfl; tid<16 fac (ILP-4).
__global__ __launch_bounds__(256, 4) void k_attn(
    const unsigned short* __restrict__ qb, const unsigned short* __restrict__ kb,
    const float2* __restrict__ lutg,
    const float* __restrict__ iw1, const float* __restrict__ ib1,
    const float* __restrict__ iw2, const float* __restrict__ ib2p,
    float* __restrict__ out) {
  __shared__ float2 Lut[LUT_N];   // 16 KB
  __shared__ float s_part[4][16];
  __shared__ float s_fac[16];

  int tid = threadIdx.x;
  int lane = tid & 63, w = tid >> 6;   // w = 128-col strip
  int i = blockIdx.x;
  int xcd = i & 7, j2 = i >> 3;        // j2 in [0,256)
  int bh = xcd * 8 + (j2 >> 5);
  int rb = j2 & 31;                    // 16-row block
  int rgrp = lane >> 4, cl = lane & 15;

  // stage LUT: 16 KB via gload16 (4 waves x 4 chunks of 1KB); published by
  // the barrier AFTER the MFMA phase (loads land under compute).
#pragma unroll
  for (int c = 0; c < 4; c++) {
    int chunk = w * 4 + c;
    gload16((const char*)lutg + chunk * 1024 + lane * 16, (char*)Lut + chunk * 1024);
  }

  // Q A-fragments for this block's 16 rows (1KB coalesced each)
  const char* Qb = (const char*)qb + (size_t)((bh * 32 + rb) * 2) * 1024;
  bf16x8 aF0 = *(const bf16x8*)(Qb + lane * 16);
  bf16x8 aF1 = *(const bf16x8*)(Qb + 1024 + lane * 16);

  const char* Kbase = (const char*)kb + (size_t)(bh * 32) * 2048;
  f32x4 zero = {0.f, 0.f, 0.f, 0.f};

  // col-block 0 (for tmax), every wave; p0 transient
  float tm1[4];
  {
    bf16x8 b0 = *(const bf16x8*)(Kbase + lane * 16);
    bf16x8 b1 = *(const bf16x8*)(Kbase + 1024 + lane * 16);
    f32x4 p0 = __builtin_amdgcn_mfma_f32_16x16x32_bf16(aF0, b0, zero, 0, 0, 0);
    p0 = __builtin_amdgcn_mfma_f32_16x16x32_bf16(aF1, b1, p0, 0, 0, 0);
    int src = lane & 48;  // cl==0 lane of this 16-group
#pragma unroll
    for (int j = 0; j < 4; j++) tm1[j] = __shfl(p0[j], src) - 1.0f;
  }

  f32x4 acc[8];
#pragma unroll
  for (int f = 0; f < 8; f++) {
    const char* Kb = Kbase + (size_t)(w * 8 + f) * 2048;
    bf16x8 b0 = *(const bf16x8*)(Kb + lane * 16);
    bf16x8 b1 = *(const bf16x8*)(Kb + 1024 + lane * 16);
    acc[f] = __builtin_amdgcn_mfma_f32_16x16x32_bf16(aF0, b0, zero, 0, 0, 0);
    acc[f] = __builtin_amdgcn_mfma_f32_16x16x32_bf16(aF1, b1, acc[f], 0, 0, 0);
  }

  __syncthreads();  // LUT visible (gloads landed during MFMA phase)

  // u0 = p*INVW + cj[j]; u0>0 <=> tp>-20; u = clamp(u0, 0, N); xu = a'*u+b'
  const float C0 = -LUT_LO * LUT_INVW;
  float cj[4];
#pragma unroll
  for (int j = 0; j < 4; j++) cj[j] = fmaf(-tm1[j], LUT_INVW, C0);

  float rowsum[4] = {0.f, 0.f, 0.f, 0.f};
#pragma unroll
  for (int f = 0; f < 8; f++) {
#pragma unroll
    for (int j = 0; j < 4; j++) {
      float u0 = fmaf(acc[f][j], LUT_INVW, cj[j]);
      float u = fminf(fmaxf(u0, 0.0f), (float)LUT_N);    // v_med3, [0, 2048]
      int bi = (int)u;
      bi = min(bi, LUT_N - 1);
      float2 ab = Lut[bi];
      float xu = fmaf(ab.x, u, ab.y);
      xu = (u0 > 0.0f) ? xu : 0.0f;
      acc[f][j] = xu;
      rowsum[j] += xu;
    }
  }

  // row partial sums across the 16 cl lanes
#pragma unroll
  for (int j = 0; j < 4; j++) {
    float s = rowsum[j];
    s += __shfl_xor(s, 1);
    s += __shfl_xor(s, 2);
    s += __shfl_xor(s, 4);
    s += __shfl_xor(s, 8);
    if (cl == 0) s_part[w][rgrp * 4 + j] = s;
  }
  __syncthreads();

  if (tid < 16) {
    float part = s_part[0][tid] + s_part[1][tid] + s_part[2][tid] + s_part[3][tid];
    float b2 = ib2p[0];
    float fac = invmlp4(part, iw1, ib1, iw2, b2);
    float pp2 = part * fac;
    if (pp2 > 1.5f) fac *= invmlp4(pp2, iw1, ib1, iw2, b2);
    s_fac[tid] = fac;
  }
  __syncthreads();

  float* outb = out + ((size_t)bh * 512 + rb * 16) * 512;
#pragma unroll
  for (int j = 0; j < 4; j++) {
    int row = rgrp * 4 + j;
    float fac = s_fac[row];
#pragma unroll
    for (int f = 0; f < 8; f++)
      __builtin_nontemporal_store(acc[f][j] * fac,
          &outb[(size_t)row * 512 + w * 128 + 16 * f + cl]);
  }
}

extern "C" void kernel_launch(void* const* d_in, const int* in_sizes, int n_in,
                              void* d_out, int out_size, void* d_ws, size_t ws_size,
                              hipStream_t stream) {
  (void)in_sizes; (void)n_in; (void)out_size; (void)ws_size;
  const float* sx  = (const float*)d_in[0];
  const float* wq  = (const float*)d_in[1];
  const float* wk  = (const float*)d_in[2];
  const float* bq  = (const float*)d_in[3];
  const float* bk  = (const float*)d_in[4];
  const float* ew1 = (const float*)d_in[5];
  const float* eb1 = (const float*)d_in[6];
  const float* ew2 = (const float*)d_in[7];
  const float* eb2 = (const float*)d_in[8];
  const float* iw1 = (const float*)d_in[9];
  const float* ib1 = (const float*)d_in[10];
  const float* iw2 = (const float*)d_in[11];
  const float* ib2 = (const float*)d_in[12];
  unsigned short* wsu = (unsigned short*)d_ws;
  float2* lut = (float2*)(wsu + LUT_OFF);
  float* out = (float*)d_out;

  k_pre<<<2568, 256, 0, stream>>>(sx, wq, wk, ew1, eb1, ew2, eb2,
                                  wsu + XS_OFF, wsu + WQ_OFF, wsu + WK_OFF, lut);
  k_proj<<<dim3(64, 4, 2), 256, 0, stream>>>(wsu + XS_OFF, wsu + WQ_OFF, bq, bk, wsu + QB_OFF);
  k_attn<<<2048, 256, 0, stream>>>(wsu + QB_OFF, wsu + KB_OFF, lut,
                                   iw1, ib1, iw2, ib2, out);
}